// Round 3
// baseline (1907.414 us; speedup 1.0000x reference)
//
#include <hip/hip_runtime.h>

// LSTM B=4096, T=512, D=H=25, 3 layers + MLP head + softmax.
// R3: 2 waves per batch (A: gate rows 0..49 = i,f ; B: rows 50..99 = g,o).
//  - ILP-4 accumulator chains in the 52-FMA dot product (R2 was one 52-deep
//    dependent chain).
//  - ONE barrier per timestep: each wave owns a private LDS [x|h] vector and
//    redundantly computes the cell update; only the activations cross waves,
//    through a parity double-buffered act[] (write p, read p after barrier;
//    next write goes to p^1, so one barrier bounds the skew).
//  - launch_bounds(256,3): ~170 VGPR cap so w[52] stays in arch VGPRs.

#define NBATCH 4096
#define NT     512
#define ND     25
#define NG     100
#define NL     3

__device__ __forceinline__ float sigf(float x) {
    return __builtin_amdgcn_rcpf(1.0f + __expf(-x));
}
__device__ __forceinline__ float tanhfast(float x) {
    float s = sigf(x + x);
    return s + s - 1.0f;
}

__global__ __launch_bounds__(256, 3)
void lstm3(const float* __restrict__ xin,
           const float* __restrict__ Wih,
           const float* __restrict__ Whh,
           const float* __restrict__ bih,
           const float* __restrict__ bhh,
           const float* __restrict__ W1,
           const float* __restrict__ b1,
           const float* __restrict__ W2,
           const float* __restrict__ b2,
           float* __restrict__ out,
           float* __restrict__ ws)
{
    // [batch-slot][role][ x(25) | h(25) | pad(6)=0 ]  -- per-wave private copy
    __shared__ __align__(16) float xh[2][2][56];
    // [batch-slot][parity][ A acts 0..49 | @56 B acts 0..49 ]
    __shared__ float act[2][2][112];

    const int wid  = threadIdx.x >> 6;
    const int lane = threadIdx.x & 63;
    const int wb   = wid >> 1;
    const int role = wid & 1;           // 0 = i,f rows; 1 = g,o rows
    const int b    = (blockIdx.x << 1) + wb;

    const int lrow = (lane < 50) ? lane : 49;   // lanes 50-63 compute garbage, never stored
    float* const myxh = xh[wb][role];

    float w[52];
    w[50] = 0.f; w[51] = 0.f;

    for (int l = 0; l < NL; ++l) {
        const int row = l * NG + role * 50 + lrow;
        const float* wihp = Wih + row * ND;
        const float* whhp = Whh + row * ND;
#pragma unroll
        for (int d = 0; d < 25; ++d) { w[d] = wihp[d]; w[25 + d] = whhp[d]; }
        const float bias = bih[row] + bhh[row];

        const float* src = (l == 0) ? (xin + (size_t)b * NT * ND)
                                    : (ws  + (size_t)b * NT * ND);
        float* wsrow = ws + (size_t)b * NT * ND;

        float c = 0.f;
        // init own xh slot: x_0, h=0, pads=0
        if (lane < 25)                    myxh[lane] = src[lane];
        else if (lane < 56)               myxh[lane] = 0.f;
        float xv_next = (lane < 25) ? src[ND + lane] : 0.f;   // x_1
        __syncthreads();   // layer-boundary: ws(prev layer) visibility + act-parity reset

        for (int t = 0; t < NT; ++t) {
            const int p = t & 1;
            // ---- dot product: 13 broadcast b128 reads, 4 independent FMA chains ----
            float a0 = bias, a1 = 0.f, a2 = 0.f, a3 = 0.f;
#pragma unroll
            for (int c4 = 0; c4 < 13; ++c4) {
                const float4 v = *(const float4*)&myxh[c4 * 4];
                a0 = fmaf(w[c4 * 4 + 0], v.x, a0);
                a1 = fmaf(w[c4 * 4 + 1], v.y, a1);
                a2 = fmaf(w[c4 * 4 + 2], v.z, a2);
                a3 = fmaf(w[c4 * 4 + 3], v.w, a3);
            }
            const float acc = (a0 + a1) + (a2 + a3);

            float a;
            if (role == 0) a = sigf(acc);                       // i, f
            else           a = (lane < 25) ? tanhfast(acc)      // g
                                           : sigf(acc);         // o
            if (lane < 50) act[wb][p][role * 56 + lane] = a;
            __syncthreads();   // the only per-timestep barrier

            // ---- redundant cell/h update in BOTH waves (lanes 0-24) ----
            if (lane < 25) {
                const float ig = act[wb][p][lane];
                const float fg = act[wb][p][25 + lane];
                const float gg = act[wb][p][56 + lane];
                const float og = act[wb][p][81 + lane];
                c = fmaf(fg, c, ig * gg);
                const float h = og * tanhfast(c);
                myxh[25 + lane] = h;          // own copy: no 2nd barrier needed
                myxh[lane]      = xv_next;    // x_{t+1}
                if (role == 0 && l < 2) wsrow[t * ND + lane] = h;
                if (t + 2 < NT) xv_next = src[(t + 2) * ND + lane];
            }
        }
    }

    // ---- head (wave A only): relu(h W1^T + b1) W2^T + b2, softmax(14) ----
    if (role == 0) {
        float* sc = act[wb][0];
        if (lane < 16) {
            float u = b1[lane];
#pragma unroll
            for (int d = 0; d < 25; ++d) u = fmaf(W1[lane * 25 + d], myxh[25 + d], u);
            sc[lane] = fmaxf(u, 0.f);
        }
        if (lane < 14) {
            float lg = b2[lane];
#pragma unroll
            for (int r = 0; r < 16; ++r) lg = fmaf(W2[lane * 16 + r], sc[r], lg);
            sc[32 + lane] = lg;
        }
        if (lane < 14) {
            float m = -1e30f;
#pragma unroll
            for (int j = 0; j < 14; ++j) m = fmaxf(m, sc[32 + j]);
            float sum = 0.f;
#pragma unroll
            for (int j = 0; j < 14; ++j) sum += __expf(sc[32 + j] - m);
            out[b * 14 + lane] = __expf(sc[32 + lane] - m) / sum;
        }
    }
}

extern "C" void kernel_launch(void* const* d_in, const int* in_sizes, int n_in,
                              void* d_out, int out_size, void* d_ws, size_t ws_size,
                              hipStream_t stream)
{
    const float* x   = (const float*)d_in[0];
    const float* Wih = (const float*)d_in[1];
    const float* Whh = (const float*)d_in[2];
    const float* bih = (const float*)d_in[3];
    const float* bhh = (const float*)d_in[4];
    const float* W1  = (const float*)d_in[5];
    const float* b1  = (const float*)d_in[6];
    const float* W2  = (const float*)d_in[7];
    const float* b2  = (const float*)d_in[8];
    float* outp = (float*)d_out;
    float* ws   = (float*)d_ws;   // 4096*512*25*4 = 209,715,200 bytes

    dim3 grid(NBATCH / 2), block(256);
    hipLaunchKernelGGL(lstm3, grid, block, 0, stream,
                       x, Wih, Whh, bih, bhh, W1, b1, W2, b2, outp, ws);
}

// Round 4
// 1846.907 us; speedup vs baseline: 1.0328x; 1.0328x over previous
//
#include <hip/hip_runtime.h>

// LSTM B=4096, T=512, D=H=25, 3 layers + MLP head + softmax.
// R4: same 2-wave-per-batch structure as R3 (wave A: rows 0..49 = i,f;
// wave B: rows 50..99 = g,o; redundant cell update; 1 barrier/t) with:
//  - v_pk_fma_f32 packed fp32 dot product (26 pk ops instead of 52 fma)
//  - raw v_exp_f32 (exp2) activations, lane-constant select hoisted out of
//    the loop (kills ocml __expf expansion and divergent branches)
//  - asm-pinned weight pairs (defeats remat/demotion; VGPR count must rise)
//  - per-timestep barrier = "s_waitcnt lgkmcnt(0); s_barrier" only (no vmcnt
//    drain; ws stores and x prefetch free-run, drained once per layer by the
//    full __syncthreads at layer boundaries)

typedef float f32x2 __attribute__((ext_vector_type(2)));

#define NBATCH 4096
#define NT     512
#define ND     25
#define NG     100
#define NL     3

__device__ __forceinline__ float exp2fast(float x) {
    float r;
    asm("v_exp_f32 %0, %1" : "=v"(r) : "v"(x));   // D = 2^S0
    return r;
}
__device__ __forceinline__ float tanhfast(float x) {
    // tanh(x) = 2/(1+2^(-2x*log2e)) - 1
    float r = __builtin_amdgcn_rcpf(1.0f + exp2fast(-2.885390082f * x));
    return fmaf(2.0f, r, -1.0f);
}

__global__ __launch_bounds__(256, 3)
void lstm4(const float* __restrict__ xin,
           const float* __restrict__ Wih,
           const float* __restrict__ Whh,
           const float* __restrict__ bih,
           const float* __restrict__ bhh,
           const float* __restrict__ W1,
           const float* __restrict__ b1,
           const float* __restrict__ W2,
           const float* __restrict__ b2,
           float* __restrict__ out,
           float* __restrict__ ws)
{
    // [batch-slot][wave-role][ x(25) | h(25) | pad(6)=0 ] -- per-wave private
    __shared__ __align__(16) float xh[2][2][56];
    // [batch-slot][parity][ A acts 0..49 | @56 B acts 0..49 ]
    __shared__ __align__(16) float act[2][2][112];

    const int wid  = threadIdx.x >> 6;
    const int lane = threadIdx.x & 63;
    const int wb   = wid >> 1;
    const int role = wid & 1;           // 0 = i,f rows; 1 = g,o rows
    const int b    = (blockIdx.x << 1) + wb;

    const int lrow = (lane < 50) ? lane : 49;   // lanes 50-63: dup row 49, never stored
    float* const myxh = xh[wb][role];
    const f32x2* const xh2 = (const f32x2*)myxh;

    // activation constants per lane (hoisted): wave A all sigmoid;
    // wave B: lanes<25 tanh (g), else sigmoid (o).
    const bool  isg    = (role == 1) && (lane < 25);
    const float emul   = isg ? -2.885390082f : -1.442695041f;  // -2log2e / -log2e
    const float ascale = isg ?  2.0f : 1.0f;
    const float abias  = isg ? -1.0f : 0.0f;

    float* const actw0 = &act[wb][0][role * 56 + lane];
    float* const actw1 = &act[wb][1][role * 56 + lane];

    for (int l = 0; l < NL; ++l) {
        const int row = l * NG + role * 50 + lrow;
        const float* wihp = Wih + row * ND;
        const float* whhp = Whh + row * ND;

        // packed weights: concat(wih[0..24], whh[0..24], 0, 0) as 26 f32x2
        f32x2 w2[26];
#pragma unroll
        for (int k = 0; k < 26; ++k) {
            const int i0 = 2 * k, i1 = i0 + 1;
            const float e0 = (i0 < 25) ? wihp[i0] : ((i0 < 50) ? whhp[i0 - 25] : 0.f);
            const float e1 = (i1 < 25) ? wihp[i1] : ((i1 < 50) ? whhp[i1 - 25] : 0.f);
            w2[k] = (f32x2){e0, e1};
            asm volatile("" : "+v"(w2[k]));   // pin in VGPRs: no remat/demotion
        }
        const float bias = bih[row] + bhh[row];

        const float* src = (l == 0) ? (xin + (size_t)b * NT * ND)
                                    : (ws  + (size_t)b * NT * ND);
        float* wsrow = ws + (size_t)b * NT * ND;

        float c = 0.f;
        if (lane < 25)       myxh[lane] = src[lane];   // x_0
        else if (lane < 56)  myxh[lane] = 0.f;         // h = 0 + pads
        float xv_next = (lane < 25) ? src[ND + lane] : 0.f;   // x_1
        __syncthreads();   // layer boundary: full drain (ws visibility)

        for (int t = 0; t < NT; ++t) {
            // ---- dot: 26 ds_read_b64 broadcasts + 26 v_pk_fma_f32 ----
            f32x2 a01 = {bias, 0.f}, a23 = {0.f, 0.f};
#pragma unroll
            for (int k = 0; k < 26; k += 2) {
                f32x2 v0 = xh2[k], v1 = xh2[k + 1];
                asm("v_pk_fma_f32 %0, %1, %2, %0" : "+v"(a01) : "v"(w2[k]),     "v"(v0));
                asm("v_pk_fma_f32 %0, %1, %2, %0" : "+v"(a23) : "v"(w2[k + 1]), "v"(v1));
            }
            const float accv = (a01.x + a23.x) + (a01.y + a23.y);

            // ---- activation: a = ascale * rcp(1 + 2^(emul*acc)) + abias ----
            const float a = fmaf(ascale,
                                 __builtin_amdgcn_rcpf(1.0f + exp2fast(emul * accv)),
                                 abias);

            float* const actw = (t & 1) ? actw1 : actw0;
            const float* const actr = (t & 1) ? &act[wb][1][0] : &act[wb][0][0];
            if (lane < 50) *actw = a;

            // LDS-only barrier: no vmcnt drain (ws stores / x loads free-run)
            asm volatile("s_waitcnt lgkmcnt(0)\n\ts_barrier" ::: "memory");

            // ---- redundant cell/h update in both waves (lanes 0-24) ----
            if (lane < 25) {
                const float ig = actr[lane];
                const float fg = actr[25 + lane];
                const float gg = actr[56 + lane];
                const float og = actr[81 + lane];
                c = fmaf(fg, c, ig * gg);
                const float h = og * tanhfast(c);
                myxh[25 + lane] = h;          // h_t (own copy; no 2nd barrier)
                myxh[lane]      = xv_next;    // x_{t+1}
                if (role == 0 && l < 2) wsrow[t * ND + lane] = h;
                if (t + 2 < NT) xv_next = src[(t + 2) * ND + lane];
            }
        }
        __syncthreads();   // layer end: drain ws stores before next layer reads
    }

    // ---- head (wave A only): relu(h W1^T + b1) W2^T + b2, softmax(14) ----
    if (role == 0) {
        float* sc = act[wb][0];
        if (lane < 16) {
            float u = b1[lane];
#pragma unroll
            for (int d = 0; d < 25; ++d) u = fmaf(W1[lane * 25 + d], myxh[25 + d], u);
            sc[lane] = fmaxf(u, 0.f);
        }
        if (lane < 14) {
            float lg = b2[lane];
#pragma unroll
            for (int r = 0; r < 16; ++r) lg = fmaf(W2[lane * 16 + r], sc[r], lg);
            sc[32 + lane] = lg;
        }
        if (lane < 14) {
            float m = -1e30f;
#pragma unroll
            for (int j = 0; j < 14; ++j) m = fmaxf(m, sc[32 + j]);
            float sum = 0.f;
#pragma unroll
            for (int j = 0; j < 14; ++j) sum += __expf(sc[32 + j] - m);
            out[b * 14 + lane] = __expf(sc[32 + lane] - m) / sum;
        }
    }
}

extern "C" void kernel_launch(void* const* d_in, const int* in_sizes, int n_in,
                              void* d_out, int out_size, void* d_ws, size_t ws_size,
                              hipStream_t stream)
{
    const float* x   = (const float*)d_in[0];
    const float* Wih = (const float*)d_in[1];
    const float* Whh = (const float*)d_in[2];
    const float* bih = (const float*)d_in[3];
    const float* bhh = (const float*)d_in[4];
    const float* W1  = (const float*)d_in[5];
    const float* b1  = (const float*)d_in[6];
    const float* W2  = (const float*)d_in[7];
    const float* b2  = (const float*)d_in[8];
    float* outp = (float*)d_out;
    float* ws   = (float*)d_ws;   // 4096*512*25*4 = 209,715,200 bytes

    dim3 grid(NBATCH / 2), block(256);
    hipLaunchKernelGGL(lstm4, grid, block, 0, stream,
                       x, Wih, Whh, bih, bhh, W1, b1, W2, b2, outp, ws);
}